// Round 28
// baseline (128.181 us; speedup 1.0000x reference)
//
#include <hip/hip_runtime.h>
#include <math.h>

#define B_ 4
#define S_ 2048
#define E_ 1024
#define H_ 16
#define D_ 64
#define MTOT (B_*S_)

typedef _Float16 half8v __attribute__((ext_vector_type(8)));
typedef _Float16 half4v __attribute__((ext_vector_type(4)));
typedef float f32x4 __attribute__((ext_vector_type(4)));
typedef float f32x16 __attribute__((ext_vector_type(16)));
typedef unsigned uint4v __attribute__((ext_vector_type(4)));

typedef __attribute__((address_space(1))) const void gconst_void;
typedef __attribute__((address_space(3))) void lds_void;

#define MFMA16(a,b,c) __builtin_amdgcn_mfma_f32_16x16x32_f16((a),(b),(c),0,0,0)
#define MFMA32(a,b,c) __builtin_amdgcn_mfma_f32_32x32x16_f16((a),(b),(c),0,0,0)

#define QSCALE 0.18033688011112042f  /* 0.125 * log2(e): folded into Q at projection */

static __device__ __forceinline__ unsigned cvt_pk_u32(float a, float b) {
  return __builtin_bit_cast(unsigned, __builtin_amdgcn_cvt_pkrtz(a, b));
}

#if __has_builtin(__builtin_amdgcn_permlane32_swap)
static __device__ __forceinline__ void pl32_swap(unsigned a, unsigned b,
                                                 unsigned& rlo, unsigned& rhi) {
  auto r = __builtin_amdgcn_permlane32_swap(a, b, false, false);
  rlo = r[0]; rhi = r[1];
}
#else
static __device__ __forceinline__ void pl32_swap(unsigned a, unsigned b,
                                                 unsigned& rlo, unsigned& rhi) {
  const int hi = (threadIdx.x & 63) >> 5;
  unsigned t = __shfl_xor(hi ? a : b, 32);
  rlo = hi ? t : a;
  rhi = hi ? b : t;
}
#endif

static __device__ __forceinline__ float partner32(float v, int hi) {
  unsigned u = __builtin_bit_cast(unsigned, v);
  unsigned lo_, hi_;
  pl32_swap(u, u, lo_, hi_);
  return __builtin_bit_cast(float, hi ? lo_ : hi_);
}

// ---------------- FUSED mask prep + weight convert (pad to 256) ----------------
__global__ __launch_bounds__(256) void mask_prep_w(
    const unsigned char* __restrict__ mraw,
    _Float16* __restrict__ maskc, float* __restrict__ qmask,
    int* __restrict__ ks, int* __restrict__ nkpa,
    const float* __restrict__ w0, const float* __restrict__ w1,
    const float* __restrict__ w2, const float* __restrict__ w3,
    _Float16* __restrict__ o0, _Float16* __restrict__ o1,
    _Float16* __restrict__ o2, _Float16* __restrict__ o3) {
  const int gid = blockIdx.x;
  const int tid = threadIdx.x;
  if (gid >= 4) {
    const int rid = gid - 4;
    const int wsel = rid >> 10, blk = rid & 1023;
    const float* in = (wsel == 0) ? w0 : (wsel == 1) ? w1 : (wsel == 2) ? w2 : w3;
    _Float16* o = (wsel == 0) ? o0 : (wsel == 1) ? o1 : (wsel == 2) ? o2 : o3;
    const int i = (blk * 256 + tid) * 4;
    float4 v = *(const float4*)(in + i);
    half4v h;
    h[0] = (_Float16)v.x; h[1] = (_Float16)v.y; h[2] = (_Float16)v.z; h[3] = (_Float16)v.w;
    *(half4v*)(o + i) = h;
    return;
  }
  __shared__ int flags[2];
  __shared__ int psum[256];
  const int b = gid;
  if (tid < 2) flags[tid] = 1;
  __syncthreads();
  const unsigned int* w = (const unsigned int*)mraw;
  for (int i = tid; i < 2048; i += 256) {
    unsigned int v = w[i];
    if (!(v == 0u || v == 1u)) flags[0] = 0;
    if (!(v == 0u || v == 0x3f800000u)) flags[1] = 0;
  }
  __syncthreads();
  const int is_i32 = flags[0], is_f32 = flags[1];
  int m[8]; int cnt = 0;
  for (int i = 0; i < 8; ++i) {
    const int idx = b * 2048 + tid * 8 + i;
    int mv;
    if (is_i32)      mv = ((const int*)mraw)[idx];
    else if (is_f32) mv = (((const unsigned int*)mraw)[idx] != 0u);
    else             mv = (mraw[idx] != 0);
    m[i] = mv; cnt += mv;
    qmask[idx] = mv ? 1.0f : 0.0f;
  }
  psum[tid] = cnt;
  __syncthreads();
  for (int off = 1; off < 256; off <<= 1) {
    int u = (tid >= off) ? psum[tid - off] : 0;
    __syncthreads();
    psum[tid] += u;
    __syncthreads();
  }
  const int total = psum[255];
  int base = psum[tid] - cnt;
  for (int i = 0; i < 8; ++i)
    if (m[i]) ks[b * 2048 + (base++)] = tid * 8 + i;
  for (int j = tid; j < 2048; j += 256)
    maskc[b * 2048 + j] = (j < total) ? (_Float16)0.0f : (_Float16)(-60000.0f);
  __syncthreads();
  const int lastv = (total > 0) ? ks[b * 2048 + total - 1] : 0;
  for (int j = total + tid; j < 2048; j += 256)
    ks[b * 2048 + j] = lastv;
  if (tid == 0) nkpa[b] = (total + 255) & ~255;  // pad to 256 for qkv M-tiles
}

// ---------------- FUSED prep (mask-dependent): x gather-convert + masked-row zero ----------------
__global__ __launch_bounds__(256) void prep_fused(
    const float* __restrict__ x, const int* __restrict__ ks,
    const int* __restrict__ nkpa, _Float16* __restrict__ xc,
    const float* __restrict__ qmask, float* __restrict__ out) {
  const int id = blockIdx.x;
  if (id < 8192) {
    const int j = id & 2047, b = id >> 11;
    if (j >= nkpa[b]) return;
    const int s = ks[b * 2048 + j];
    const float* src = x + (size_t)(b * 2048 + s) * E_;
    _Float16* dst = xc + (size_t)(b * 2048 + j) * E_;
    const int i = threadIdx.x * 4;
    float4 v = *(const float4*)(src + i);
    half4v h;
    h[0] = (_Float16)v.x; h[1] = (_Float16)v.y; h[2] = (_Float16)v.z; h[3] = (_Float16)v.w;
    *(half4v*)(dst + i) = h;
  } else {
    const int row = id - 8192;
    if (qmask[row] != 0.0f) return;
    float4 z = make_float4(0.f, 0.f, 0.f, 0.f);
    *(float4*)(out + (size_t)row * E_ + threadIdx.x * 4) = z;
  }
}

// ---------------- swizzled staging: ROWS x 64 f16 -> LDS (256-thread blocks) ----------------
template <int ROWS>
__device__ __forceinline__ void stageX64s(const _Float16* __restrict__ g, int ld,
                                          _Float16* lds, int wid, int lane) {
#pragma unroll
  for (int j = 0; j < ROWS / 32; ++j) {
    const int c = j * 256 + wid * 64 + lane;
    const int row = c >> 3, dslot = c & 7;
    const int sslot = dslot ^ (row & 7);
    const _Float16* src = g + (size_t)row * ld + sslot * 8;
    _Float16* dst = lds + (size_t)(j * 256 + wid * 64) * 8;
    __builtin_amdgcn_global_load_lds((gconst_void*)src, (lds_void*)dst, 16, 0, 0);
  }
}

// ---------------- swizzled staging for 512-thread blocks: A 256x64 (4 ld), B 128x64 (2 ld) ----------------
__device__ __forceinline__ void stageA256(const _Float16* __restrict__ g,
                                          _Float16* lds, int wid, int lane) {
#pragma unroll
  for (int j = 0; j < 4; ++j) {
    const int c = j * 512 + wid * 64 + lane;
    const int row = c >> 3, dslot = c & 7;
    const int sslot = dslot ^ (row & 7);
    const _Float16* src = g + (size_t)row * E_ + sslot * 8;
    _Float16* dst = lds + (size_t)(j * 512 + wid * 64) * 8;
    __builtin_amdgcn_global_load_lds((gconst_void*)src, (lds_void*)dst, 16, 0, 0);
  }
}
__device__ __forceinline__ void stageB128(const _Float16* __restrict__ g,
                                          _Float16* lds, int wid, int lane) {
#pragma unroll
  for (int j = 0; j < 2; ++j) {
    const int c = j * 512 + wid * 64 + lane;
    const int row = c >> 3, dslot = c & 7;
    const int sslot = dslot ^ (row & 7);
    const _Float16* src = g + (size_t)row * E_ + sslot * 8;
    _Float16* dst = lds + (size_t)(j * 512 + wid * 64) * 8;
    __builtin_amdgcn_global_load_lds((gconst_void*)src, (lds_void*)dst, 16, 0, 0);
  }
}

// ---------------- QKV GEMM: 256x128 tile, BK=64, 3-DEEP RING + COUNTED VMCNT (T3+T4) ----------------
// 512 thr = 8 waves (4M x 2N), acc[4][4]. LDS ring: 3 x (A 32KB + B 16KB) = 144KB.
// Per step: ds_read(slot t%3) | stage(slot (t+2)%3) | vmcnt(6) | 32 MFMA | s_barrier.
// Grid 768: tt = id/24 (0..31) -> bb = tt>>3, mtile = tt&7; rem -> by(8), z(3).
__global__ __launch_bounds__(512) void qkv_gemm(
    const _Float16* __restrict__ xc, const int* __restrict__ nkpa,
    const _Float16* __restrict__ wq, const _Float16* __restrict__ wk, const _Float16* __restrict__ wv,
    const float* __restrict__ bq, const float* __restrict__ bkp, const float* __restrict__ bvp,
    _Float16* __restrict__ Qc, _Float16* __restrict__ Kc, _Float16* __restrict__ Vc) {
  const int id = blockIdx.x;
  const int tt = id / 24;
  const int rem = id % 24;
  const int by = rem / 3, z = rem % 3;
  const int bb = tt >> 3, mtile = tt & 7;
  if (mtile * 256 >= nkpa[bb]) return;  // block-uniform exit before any barrier
  __shared__ _Float16 Asr[3 * 256 * 64];   // 96KB
  __shared__ _Float16 Bsr[3 * 128 * 64];   // 48KB
  const int tid = threadIdx.x, lane = tid & 63, wid = tid >> 6;
  const int g = lane >> 4, r16 = lane & 15;
  const int wr = wid >> 1, wc = wid & 1;
  const int sw = r16 & 7;
  const int bm = bb * 2048 + mtile * 256, bn = by * 128;
  const _Float16* w = (z == 0) ? wq : (z == 1) ? wk : wv;
  const float* bias = (z == 0) ? bq : (z == 1) ? bkp : bvp;
  const _Float16* Abase = xc + (size_t)bm * E_;
  const _Float16* Bbase = w + (size_t)bn * E_;
  f32x4 acc[4][4] = {};
  // prologue: stage K-tiles 0,1 into slots 0,1; verify tile 0 landed (6 newer loads outstanding)
  stageA256(Abase + 0, Asr, wid, lane);
  stageB128(Bbase + 0, Bsr, wid, lane);
  stageA256(Abase + 64, Asr + 256 * 64, wid, lane);
  stageB128(Bbase + 64, Bsr + 128 * 64, wid, lane);
  asm volatile("s_waitcnt vmcnt(6)" ::: "memory");
  __builtin_amdgcn_s_barrier();
  for (int t = 0; t < 16; ++t) {
    const int slot = t % 3;
    const _Float16* Ac = Asr + slot * (256 * 64);
    const _Float16* Bc = Bsr + slot * (128 * 64);
    half8v a[2][4], bfr[2][4];
#pragma unroll
    for (int kk = 0; kk < 2; ++kk) {
      const int so = ((kk * 4 + g) ^ sw) * 8;
#pragma unroll
      for (int i = 0; i < 4; ++i)
        a[kk][i] = *(const half8v*)&Ac[(wr * 64 + i * 16 + r16) * 64 + so];
#pragma unroll
      for (int j = 0; j < 4; ++j)
        bfr[kk][j] = *(const half8v*)&Bc[(wc * 64 + j * 16 + r16) * 64 + so];
    }
    if (t < 14) {
      const int s2 = (t + 2) % 3;
      stageA256(Abase + (size_t)(t + 2) * 64, Asr + s2 * (256 * 64), wid, lane);
      stageB128(Bbase + (size_t)(t + 2) * 64, Bsr + s2 * (128 * 64), wid, lane);
      asm volatile("s_waitcnt vmcnt(6)" ::: "memory");   // stage t+1 retired; t+2 in flight
    } else if (t == 14) {
      asm volatile("s_waitcnt vmcnt(0)" ::: "memory");   // final tile (15) landed
    }
    __builtin_amdgcn_s_setprio(1);
#pragma unroll
    for (int kk = 0; kk < 2; ++kk)
#pragma unroll
      for (int i = 0; i < 4; ++i)
#pragma unroll
        for (int j = 0; j < 4; ++j)
          acc[i][j] = MFMA16(a[kk][i], bfr[kk][j], acc[i][j]);
    __builtin_amdgcn_s_setprio(0);
    __builtin_amdgcn_s_barrier();   // broadcasts vmcnt guarantee; guards ring-slot reuse
  }
#pragma unroll
  for (int i = 0; i < 4; ++i) {
#pragma unroll
    for (int j = 0; j < 4; ++j) {
      const int gn = bn + wc * 64 + j * 16 + r16;
      const float bb2 = bias[gn];
      const int h = gn >> 6, d = gn & 63;
      const int gm0 = bm + wr * 64 + i * 16 + g * 4;
      const int b_ = gm0 >> 11, s0 = gm0 & (S_ - 1);
      const size_t bhbase = (size_t)(b_ * H_ + h) * S_ * D_;
      if (z == 2) {
        half4v v4;
#pragma unroll
        for (int ii = 0; ii < 4; ++ii) v4[ii] = (_Float16)(acc[i][j][ii] + bb2);
        *(half4v*)&Vc[bhbase + (size_t)(s0 >> 4) * (D_ * 16) + d * 16 + (s0 & 15)] = v4;
      } else if (z == 1) {
#pragma unroll
        for (int ii = 0; ii < 4; ++ii) {
          const int s = s0 + ii;
          Kc[bhbase + (size_t)(s >> 5) * 2048 + (d >> 4) * 512 + (s & 31) * 16 + (d & 15)] =
              (_Float16)(acc[i][j][ii] + bb2);
        }
      } else {
#pragma unroll
        for (int ii = 0; ii < 4; ++ii)
          Qc[bhbase + (size_t)(s0 + ii) * D_ + d] = (_Float16)((acc[i][j][ii] + bb2) * QSCALE);
      }
    }
  }
}

// ---------------- flash attention v15: k-split x4, tree merge, 64 q-rows/block ----------------
__global__ __launch_bounds__(512) void attn_kernel(
    const _Float16* __restrict__ Qc, const _Float16* __restrict__ Kc, const _Float16* __restrict__ Vc,
    const _Float16* __restrict__ maskc, const int* __restrict__ nkpa,
    _Float16* __restrict__ Oc) {
  __shared__ float mlds[2][2][64][36];
  _Float16* smask = (_Float16*)&mlds[0][0][0][0];
  const int tid = threadIdx.x, lane = tid & 63, wid = tid >> 6;
  const int c = lane & 31, hi = lane >> 5;
  const int qg = wid & 1, kh = wid >> 1;
  const int id = blockIdx.x;
  const int slot = id & 7, hbh = (id >> 3) & 7, t = id >> 6;
  const int hb = hbh * 8 + slot;
  const int b = hb >> 4, h = hb & 15;
  const int nkp = nkpa[b];
  if (t * 64 >= nkp) return;
  const size_t bh = (size_t)(b * H_ + h);
  const _Float16* Qb = Qc + bh * S_ * D_;
  const _Float16* Kb = Kc + bh * S_ * D_;
  const _Float16* Vb = Vc + bh * S_ * D_;

  *((half4v*)smask + tid) = *((const half4v*)(maskc + (size_t)b * S_) + tid);

  const int jq = t * 64 + qg * 32 + c;

  half8v qb[4];
#pragma unroll
  for (int kc = 0; kc < 4; ++kc)
    qb[kc] = *(const half8v*)&Qb[(size_t)jq * D_ + 16 * kc + 8 * hi];

  half8v bone = {};
  if (hi == 0) bone[0] = (_Float16)1.0f;
  const f32x16 fzero = {};

  f32x16 oacc[2] = {};
  float mrun = -1e30f, lrun = 0.f;
  const int laneoff = c * 16 + 8 * hi;
  const int nkq = nkp >> 2;
  const int kb0 = kh * nkq;

  __syncthreads();

  half8v kaf[4];
  {
    const _Float16* ktb = Kb + (size_t)(kb0 >> 5) * 2048 + laneoff;
#pragma unroll
    for (int kc = 0; kc < 4; ++kc) kaf[kc] = *(const half8v*)&ktb[kc * 512];
  }
  _Float16 mv = smask[kb0 + c];

  for (int kb = kb0; kb < kb0 + nkq; kb += 32) {
    half8v amask = {};
    if (hi == 0) amask[0] = mv;
    __builtin_amdgcn_s_setprio(1);
    f32x16 sc = MFMA32(amask, bone, fzero);
    sc = MFMA32(kaf[0], qb[0], sc);
    sc = MFMA32(kaf[1], qb[1], sc);
    sc = MFMA32(kaf[2], qb[2], sc);
    sc = MFMA32(kaf[3], qb[3], sc);
    __builtin_amdgcn_s_setprio(0);
    const int kbn = (kb + 32 < kb0 + nkq) ? kb + 32 : kb0;
    {
      const _Float16* ktb = Kb + (size_t)(kbn >> 5) * 2048 + laneoff;
#pragma unroll
      for (int kc = 0; kc < 4; ++kc) kaf[kc] = *(const half8v*)&ktb[kc * 512];
    }
    mv = smask[kbn + c];
    const _Float16* v_base = Vb + (size_t)(kb >> 4) * (D_ * 16) + laneoff;
    half8v va00 = *(const half8v*)&v_base[0];
    half8v va01 = *(const half8v*)&v_base[512];
    half8v va10 = *(const half8v*)&v_base[1024];
    half8v va11 = *(const half8v*)&v_base[1024 + 512];
    float t0 = fmaxf(sc[0], sc[4]), t1 = fmaxf(sc[1], sc[5]);
    float t2 = fmaxf(sc[2], sc[6]), t3 = fmaxf(sc[3], sc[7]);
    t0 = fmaxf(fmaxf(sc[8], sc[12]), t0);
    t1 = fmaxf(fmaxf(sc[9], sc[13]), t1);
    t2 = fmaxf(fmaxf(sc[10], sc[14]), t2);
    t3 = fmaxf(fmaxf(sc[11], sc[15]), t3);
    float pmax = fmaxf(fmaxf(t0, t1), fmaxf(t2, t3));
    pmax = fmaxf(pmax, partner32(pmax, hi));
    if (__any(pmax > mrun + 11.0f)) {
      float mnew = fmaxf(mrun, pmax);
      float corr = __builtin_amdgcn_exp2f(mrun - mnew);
      mrun = mnew;
      lrun *= corr;
#pragma unroll
      for (int dt = 0; dt < 2; ++dt)
#pragma unroll
        for (int r = 0; r < 16; ++r) oacc[dt][r] *= corr;
    }
    float ps0 = 0.f, ps1 = 0.f;
#pragma unroll
    for (int sl = 0; sl < 2; ++sl) {
      const int bs = 8 * sl;
      float p0 = __builtin_amdgcn_exp2f(sc[bs + 0] - mrun);
      float p1 = __builtin_amdgcn_exp2f(sc[bs + 1] - mrun);
      float p2 = __builtin_amdgcn_exp2f(sc[bs + 2] - mrun);
      float p3 = __builtin_amdgcn_exp2f(sc[bs + 3] - mrun);
      float p4 = __builtin_amdgcn_exp2f(sc[bs + 4] - mrun);
      float p5 = __builtin_amdgcn_exp2f(sc[bs + 5] - mrun);
      float p6 = __builtin_amdgcn_exp2f(sc[bs + 6] - mrun);
      float p7 = __builtin_amdgcn_exp2f(sc[bs + 7] - mrun);
      ps0 += (p0 + p1) + (p2 + p3);
      ps1 += (p4 + p5) + (p6 + p7);
      unsigned uA = cvt_pk_u32(p0, p1);
      unsigned uB = cvt_pk_u32(p2, p3);
      unsigned uC = cvt_pk_u32(p4, p5);
      unsigned uD = cvt_pk_u32(p6, p7);
      unsigned w0, w1, w2, w3;
      pl32_swap(uA, uC, w0, w2);
      pl32_swap(uB, uD, w1, w3);
      uint4v u4 = {w0, w1, w2, w3};
      half8v pb = __builtin_bit_cast(half8v, u4);
      __builtin_amdgcn_s_setprio(1);
      oacc[0] = MFMA32(sl ? va10 : va00, pb, oacc[0]);
      oacc[1] = MFMA32(sl ? va11 : va01, pb, oacc[1]);
      __builtin_amdgcn_s_setprio(0);
    }
    lrun += ps0 + ps1;
  }
  lrun += partner32(lrun, hi);
  __syncthreads();
  if (kh >= 2) {
    float* p = &mlds[qg][kh - 2][lane][0];
#pragma unroll
    for (int dt = 0; dt < 2; ++dt)
#pragma unroll
      for (int rr = 0; rr < 4; ++rr) {
        float4 v4 = make_float4(oacc[dt][4 * rr], oacc[dt][4 * rr + 1],
                                oacc[dt][4 * rr + 2], oacc[dt][4 * rr + 3]);
        *(float4*)&p[dt * 16 + rr * 4] = v4;
      }
    p[32] = mrun;
    p[33] = lrun;
  }
  __syncthreads();
  if (kh < 2) {
    const float* p = &mlds[qg][kh][lane][0];
    const float mB = p[32], lB = p[33];
    const float mS = fmaxf(mrun, mB);
    const float cA = __builtin_amdgcn_exp2f(mrun - mS);
    const float cB = __builtin_amdgcn_exp2f(mB - mS);
#pragma unroll
    for (int dt = 0; dt < 2; ++dt)
#pragma unroll
      for (int rr = 0; rr < 4; ++rr) {
        float4 vB = *(const float4*)&p[dt * 16 + rr * 4];
        oacc[dt][4 * rr + 0] = oacc[dt][4 * rr + 0] * cA + vB.x * cB;
        oacc[dt][4 * rr + 1] = oacc[dt][4 * rr + 1] * cA + vB.y * cB;
        oacc[dt][4 * rr + 2] = oacc[dt][4 * rr + 2] * cA + vB.z * cB;
        oacc[dt][4 * rr + 3] = oacc[dt][4 * rr + 3] * cA + vB.w * cB;
      }
    lrun = lrun * cA + lB * cB;
    mrun = mS;
  }
  __syncthreads();
  if (kh == 1) {
    float* p = &mlds[qg][0][lane][0];
#pragma unroll
    for (int dt = 0; dt < 2; ++dt)
#pragma unroll
      for (int rr = 0; rr < 4; ++rr) {
        float4 v4 = make_float4(oacc[dt][4 * rr], oacc[dt][4 * rr + 1],
                                oacc[dt][4 * rr + 2], oacc[dt][4 * rr + 3]);
        *(float4*)&p[dt * 16 + rr * 4] = v4;
      }
    p[32] = mrun;
    p[33] = lrun;
  }
  __syncthreads();
  if (kh == 0) {
    const float* p = &mlds[qg][0][lane][0];
    const float mB = p[32], lB = p[33];
    const float mS = fmaxf(mrun, mB);
    const float cA = __builtin_amdgcn_exp2f(mrun - mS);
    const float cB = __builtin_amdgcn_exp2f(mB - mS);
    const float inv = 1.0f / (lrun * cA + lB * cB);
    const float fA = cA * inv, fB = cB * inv;
    _Float16* orow = Oc + ((size_t)(b * S_ + jq)) * E_ + h * D_;
#pragma unroll
    for (int dt = 0; dt < 2; ++dt)
#pragma unroll
      for (int rr = 0; rr < 4; ++rr) {
        float4 vB = *(const float4*)&p[dt * 16 + rr * 4];
        half4v o4;
        o4[0] = (_Float16)(oacc[dt][4 * rr + 0] * fA + vB.x * fB);
        o4[1] = (_Float16)(oacc[dt][4 * rr + 1] * fA + vB.y * fB);
        o4[2] = (_Float16)(oacc[dt][4 * rr + 2] * fA + vB.z * fB);
        o4[3] = (_Float16)(oacc[dt][4 * rr + 3] * fA + vB.w * fB);
        *(half4v*)&orow[32 * dt + 8 * rr + 4 * hi] = o4;
      }
  }
}

// ---------------- output projection: 64x128, BK=64 swizzled, dbuf, row scatter ----------------
__global__ __launch_bounds__(256) void oproj_gemm(
    const _Float16* __restrict__ Oc, const _Float16* __restrict__ wo, const float* __restrict__ bo,
    const int* __restrict__ ks, const int* __restrict__ nkpa, float* __restrict__ out) {
  const int id = blockIdx.x;
  const int jt = id / 32;
  const int rem = id % 32;
  const int bb = rem / 8, by = rem % 8;
  if (jt * 64 >= nkpa[bb]) return;
  __shared__ _Float16 As[2][64 * 64];
  __shared__ _Float16 Bs[2][128 * 64];
  const int tid = threadIdx.x, lane = tid & 63, wid = tid >> 6;
  const int g = lane >> 4, r16 = lane & 15;
  const int bm = bb * 2048 + jt * 64, bn = by * 128;
  const int wr = wid >> 1, wc = wid & 1;
  const int sw = r16 & 7;
  f32x4 acc[2][4] = {};
  stageX64s<64>(Oc + (size_t)bm * E_, E_, As[0], wid, lane);
  stageX64s<128>(wo + (size_t)bn * E_, E_, Bs[0], wid, lane);
  __syncthreads();
  int cur = 0;
  for (int k0 = 0; k0 < E_; k0 += 64) {
    const int kn = k0 + 64;
    if (kn < E_) {
      stageX64s<64>(Oc + (size_t)bm * E_ + kn, E_, As[cur ^ 1], wid, lane);
      stageX64s<128>(wo + (size_t)bn * E_ + kn, E_, Bs[cur ^ 1], wid, lane);
    }
    const _Float16* Ac = As[cur];
    const _Float16* Bc = Bs[cur];
#pragma unroll
    for (int kk = 0; kk < 2; ++kk) {
      const int so = ((kk * 4 + g) ^ sw) * 8;
      half8v a[2], bf[4];
#pragma unroll
      for (int i = 0; i < 2; ++i) a[i] = *(const half8v*)&Ac[(wr * 32 + i * 16 + r16) * 64 + so];
#pragma unroll
      for (int j = 0; j < 4; ++j) bf[j] = *(const half8v*)&Bc[(wc * 64 + j * 16 + r16) * 64 + so];
#pragma unroll
      for (int i = 0; i < 2; ++i)
#pragma unroll
        for (int j = 0; j < 4; ++j) acc[i][j] = MFMA16(a[i], bf[j], acc[i][j]);
    }
    __syncthreads();
    cur ^= 1;
  }
#pragma unroll
  for (int i = 0; i < 2; ++i) {
#pragma unroll
    for (int j = 0; j < 4; ++j) {
      const int gn = bn + wc * 64 + j * 16 + r16;
      const float bb2 = bo[gn];
      const int gm0 = bm + wr * 32 + i * 16 + g * 4;
#pragma unroll
      for (int ii = 0; ii < 4; ++ii) {
        const int gm = gm0 + ii;
        const int b_ = gm >> 11, j_ = gm & (S_ - 1);
        const int sorig = ks[b_ * 2048 + j_];
        const float y = acc[i][j][ii] + bb2;
        out[((size_t)(b_ * S_ + sorig)) * E_ + gn] = fabsf(y);
      }
    }
  }
}

extern "C" void kernel_launch(void* const* d_in, const int* in_sizes, int n_in,
                              void* d_out, int out_size, void* d_ws, size_t ws_size,
                              hipStream_t stream) {
  const float* x = (const float*)d_in[0];
  const unsigned char* mask = (const unsigned char*)d_in[1];
  const float* WQ_w = (const float*)d_in[2];
  const float* WQ_b = (const float*)d_in[3];
  const float* WK_w = (const float*)d_in[4];
  const float* WK_b = (const float*)d_in[5];
  const float* WV_w = (const float*)d_in[6];
  const float* WV_b = (const float*)d_in[7];
  const float* WO_w = (const float*)d_in[8];
  const float* WO_b = (const float*)d_in[9];

  char* ws = (char*)d_ws;
  size_t off = 0;
  _Float16* xc  = (_Float16*)(ws + off); off += (size_t)MTOT * E_ * 2;
  _Float16* wqh = (_Float16*)(ws + off); off += (size_t)E_ * E_ * 2;
  _Float16* wkh = (_Float16*)(ws + off); off += (size_t)E_ * E_ * 2;
  _Float16* wvh = (_Float16*)(ws + off); off += (size_t)E_ * E_ * 2;
  _Float16* woh = (_Float16*)(ws + off); off += (size_t)E_ * E_ * 2;
  _Float16* Qc  = (_Float16*)(ws + off); off += (size_t)MTOT * E_ * 2;
  _Float16* Kc  = (_Float16*)(ws + off); off += (size_t)MTOT * E_ * 2;
  _Float16* Vc  = (_Float16*)(ws + off); off += (size_t)MTOT * E_ * 2;
  _Float16* Oc  = (_Float16*)(ws + off); off += (size_t)MTOT * E_ * 2;
  _Float16* maskcf = (_Float16*)(ws + off); off += (size_t)B_ * S_ * 2;
  float* qmaskf = (float*)(ws + off); off += (size_t)B_ * S_ * 4;
  int* ksl      = (int*)(ws + off); off += (size_t)B_ * S_ * 4;
  int* nkpa     = (int*)(ws + off); off += 64;
  if (ws_size < off) return;

  mask_prep_w<<<dim3(4100), dim3(256), 0, stream>>>(
      mask, maskcf, qmaskf, ksl, nkpa,
      WQ_w, WK_w, WV_w, WO_w, wqh, wkh, wvh, woh);
  prep_fused<<<dim3(16384), dim3(256), 0, stream>>>(
      x, ksl, nkpa, xc, qmaskf, (float*)d_out);
  qkv_gemm<<<dim3(768), dim3(512), 0, stream>>>(
      xc, nkpa, wqh, wkh, wvh, WQ_b, WK_b, WV_b, Qc, Kc, Vc);
  attn_kernel<<<dim3((S_ / 64) * H_ * B_), dim3(512), 0, stream>>>(
      Qc, Kc, Vc, maskcf, nkpa, Oc);
  oproj_gemm<<<dim3(32 * 32), dim3(256), 0, stream>>>(Oc, woh, WO_b, ksl, nkpa, (float*)d_out);
}

// Round 29
// 125.010 us; speedup vs baseline: 1.0254x; 1.0254x over previous
//
#include <hip/hip_runtime.h>
#include <math.h>

#define B_ 4
#define S_ 2048
#define E_ 1024
#define H_ 16
#define D_ 64
#define MTOT (B_*S_)

typedef _Float16 half8v __attribute__((ext_vector_type(8)));
typedef _Float16 half4v __attribute__((ext_vector_type(4)));
typedef float f32x4 __attribute__((ext_vector_type(4)));
typedef float f32x16 __attribute__((ext_vector_type(16)));
typedef unsigned uint4v __attribute__((ext_vector_type(4)));

typedef __attribute__((address_space(1))) const void gconst_void;
typedef __attribute__((address_space(3))) void lds_void;

#define MFMA16(a,b,c) __builtin_amdgcn_mfma_f32_16x16x32_f16((a),(b),(c),0,0,0)
#define MFMA32(a,b,c) __builtin_amdgcn_mfma_f32_32x32x16_f16((a),(b),(c),0,0,0)

#define QSCALE 0.18033688011112042f  /* 0.125 * log2(e): folded into Q at projection */

static __device__ __forceinline__ unsigned cvt_pk_u32(float a, float b) {
  return __builtin_bit_cast(unsigned, __builtin_amdgcn_cvt_pkrtz(a, b));
}

#if __has_builtin(__builtin_amdgcn_permlane32_swap)
static __device__ __forceinline__ void pl32_swap(unsigned a, unsigned b,
                                                 unsigned& rlo, unsigned& rhi) {
  auto r = __builtin_amdgcn_permlane32_swap(a, b, false, false);
  rlo = r[0]; rhi = r[1];
}
#else
static __device__ __forceinline__ void pl32_swap(unsigned a, unsigned b,
                                                 unsigned& rlo, unsigned& rhi) {
  const int hi = (threadIdx.x & 63) >> 5;
  unsigned t = __shfl_xor(hi ? a : b, 32);
  rlo = hi ? t : a;
  rhi = hi ? b : t;
}
#endif

static __device__ __forceinline__ float partner32(float v, int hi) {
  unsigned u = __builtin_bit_cast(unsigned, v);
  unsigned lo_, hi_;
  pl32_swap(u, u, lo_, hi_);
  return __builtin_bit_cast(float, hi ? lo_ : hi_);
}

// ---------------- FUSED mask prep + weight convert (pad to 128) ----------------
__global__ __launch_bounds__(256) void mask_prep_w(
    const unsigned char* __restrict__ mraw,
    _Float16* __restrict__ maskc, float* __restrict__ qmask,
    int* __restrict__ ks, int* __restrict__ nkpa,
    const float* __restrict__ w0, const float* __restrict__ w1,
    const float* __restrict__ w2, const float* __restrict__ w3,
    _Float16* __restrict__ o0, _Float16* __restrict__ o1,
    _Float16* __restrict__ o2, _Float16* __restrict__ o3) {
  const int gid = blockIdx.x;
  const int tid = threadIdx.x;
  if (gid >= 4) {
    const int rid = gid - 4;
    const int wsel = rid >> 10, blk = rid & 1023;
    const float* in = (wsel == 0) ? w0 : (wsel == 1) ? w1 : (wsel == 2) ? w2 : w3;
    _Float16* o = (wsel == 0) ? o0 : (wsel == 1) ? o1 : (wsel == 2) ? o2 : o3;
    const int i = (blk * 256 + tid) * 4;
    float4 v = *(const float4*)(in + i);
    half4v h;
    h[0] = (_Float16)v.x; h[1] = (_Float16)v.y; h[2] = (_Float16)v.z; h[3] = (_Float16)v.w;
    *(half4v*)(o + i) = h;
    return;
  }
  __shared__ int flags[2];
  __shared__ int psum[256];
  const int b = gid;
  if (tid < 2) flags[tid] = 1;
  __syncthreads();
  const unsigned int* w = (const unsigned int*)mraw;
  for (int i = tid; i < 2048; i += 256) {
    unsigned int v = w[i];
    if (!(v == 0u || v == 1u)) flags[0] = 0;
    if (!(v == 0u || v == 0x3f800000u)) flags[1] = 0;
  }
  __syncthreads();
  const int is_i32 = flags[0], is_f32 = flags[1];
  int m[8]; int cnt = 0;
  for (int i = 0; i < 8; ++i) {
    const int idx = b * 2048 + tid * 8 + i;
    int mv;
    if (is_i32)      mv = ((const int*)mraw)[idx];
    else if (is_f32) mv = (((const unsigned int*)mraw)[idx] != 0u);
    else             mv = (mraw[idx] != 0);
    m[i] = mv; cnt += mv;
    qmask[idx] = mv ? 1.0f : 0.0f;
  }
  psum[tid] = cnt;
  __syncthreads();
  for (int off = 1; off < 256; off <<= 1) {
    int u = (tid >= off) ? psum[tid - off] : 0;
    __syncthreads();
    psum[tid] += u;
    __syncthreads();
  }
  const int total = psum[255];
  int base = psum[tid] - cnt;
  for (int i = 0; i < 8; ++i)
    if (m[i]) ks[b * 2048 + (base++)] = tid * 8 + i;
  for (int j = tid; j < 2048; j += 256)
    maskc[b * 2048 + j] = (j < total) ? (_Float16)0.0f : (_Float16)(-60000.0f);
  __syncthreads();
  const int lastv = (total > 0) ? ks[b * 2048 + total - 1] : 0;
  for (int j = total + tid; j < 2048; j += 256)
    ks[b * 2048 + j] = lastv;
  if (tid == 0) nkpa[b] = (total + 127) & ~127;  // 128-pad; qkv 256-tiles tolerate partial tail
}

// ---------------- FUSED prep (mask-dependent): x gather-convert + masked-row zero ----------------
__global__ __launch_bounds__(256) void prep_fused(
    const float* __restrict__ x, const int* __restrict__ ks,
    const int* __restrict__ nkpa, _Float16* __restrict__ xc,
    const float* __restrict__ qmask, float* __restrict__ out) {
  const int id = blockIdx.x;
  if (id < 8192) {
    const int j = id & 2047, b = id >> 11;
    if (j >= nkpa[b]) return;
    const int s = ks[b * 2048 + j];
    const float* src = x + (size_t)(b * 2048 + s) * E_;
    _Float16* dst = xc + (size_t)(b * 2048 + j) * E_;
    const int i = threadIdx.x * 4;
    float4 v = *(const float4*)(src + i);
    half4v h;
    h[0] = (_Float16)v.x; h[1] = (_Float16)v.y; h[2] = (_Float16)v.z; h[3] = (_Float16)v.w;
    *(half4v*)(dst + i) = h;
  } else {
    const int row = id - 8192;
    if (qmask[row] != 0.0f) return;
    float4 z = make_float4(0.f, 0.f, 0.f, 0.f);
    *(float4*)(out + (size_t)row * E_ + threadIdx.x * 4) = z;
  }
}

// ---------------- swizzled staging: ROWS x 64 f16 -> LDS (256-thread blocks) ----------------
template <int ROWS>
__device__ __forceinline__ void stageX64s(const _Float16* __restrict__ g, int ld,
                                          _Float16* lds, int wid, int lane) {
#pragma unroll
  for (int j = 0; j < ROWS / 32; ++j) {
    const int c = j * 256 + wid * 64 + lane;
    const int row = c >> 3, dslot = c & 7;
    const int sslot = dslot ^ (row & 7);
    const _Float16* src = g + (size_t)row * ld + sslot * 8;
    _Float16* dst = lds + (size_t)(j * 256 + wid * 64) * 8;
    __builtin_amdgcn_global_load_lds((gconst_void*)src, (lds_void*)dst, 16, 0, 0);
  }
}

// ---------------- swizzled staging for 512-thread blocks: A 256x64 (4 ld), B 128x64 (2 ld) ----------------
__device__ __forceinline__ void stageA256(const _Float16* __restrict__ g,
                                          _Float16* lds, int wid, int lane) {
#pragma unroll
  for (int j = 0; j < 4; ++j) {
    const int c = j * 512 + wid * 64 + lane;
    const int row = c >> 3, dslot = c & 7;
    const int sslot = dslot ^ (row & 7);
    const _Float16* src = g + (size_t)row * E_ + sslot * 8;
    _Float16* dst = lds + (size_t)(j * 512 + wid * 64) * 8;
    __builtin_amdgcn_global_load_lds((gconst_void*)src, (lds_void*)dst, 16, 0, 0);
  }
}
__device__ __forceinline__ void stageB128(const _Float16* __restrict__ g,
                                          _Float16* lds, int wid, int lane) {
#pragma unroll
  for (int j = 0; j < 2; ++j) {
    const int c = j * 512 + wid * 64 + lane;
    const int row = c >> 3, dslot = c & 7;
    const int sslot = dslot ^ (row & 7);
    const _Float16* src = g + (size_t)row * E_ + sslot * 8;
    _Float16* dst = lds + (size_t)(j * 512 + wid * 64) * 8;
    __builtin_amdgcn_global_load_lds((gconst_void*)src, (lds_void*)dst, 16, 0, 0);
  }
}

// ---------------- QKV GEMM: 256x128 tile, BK=64, 3-DEEP RING + COUNTED VMCNT (T3+T4) ----------------
// 512 thr = 8 waves (4M x 2N), acc[4][4]. LDS ring: 3 x (A 32KB + B 16KB) = 144KB.
// Per step: ds_read(slot t%3) | stage(slot (t+2)%3) | vmcnt(6) | 32 MFMA | s_barrier.
// Partial last M-tile reads finite poison rows (never consumed downstream) — safe.
__global__ __launch_bounds__(512) void qkv_gemm(
    const _Float16* __restrict__ xc, const int* __restrict__ nkpa,
    const _Float16* __restrict__ wq, const _Float16* __restrict__ wk, const _Float16* __restrict__ wv,
    const float* __restrict__ bq, const float* __restrict__ bkp, const float* __restrict__ bvp,
    _Float16* __restrict__ Qc, _Float16* __restrict__ Kc, _Float16* __restrict__ Vc) {
  const int id = blockIdx.x;
  const int tt = id / 24;
  const int rem = id % 24;
  const int by = rem / 3, z = rem % 3;
  const int bb = tt >> 3, mtile = tt & 7;
  if (mtile * 256 >= nkpa[bb]) return;  // block-uniform exit before any barrier
  __shared__ _Float16 Asr[3 * 256 * 64];   // 96KB
  __shared__ _Float16 Bsr[3 * 128 * 64];   // 48KB
  const int tid = threadIdx.x, lane = tid & 63, wid = tid >> 6;
  const int g = lane >> 4, r16 = lane & 15;
  const int wr = wid >> 1, wc = wid & 1;
  const int sw = r16 & 7;
  const int bm = bb * 2048 + mtile * 256, bn = by * 128;
  const _Float16* w = (z == 0) ? wq : (z == 1) ? wk : wv;
  const float* bias = (z == 0) ? bq : (z == 1) ? bkp : bvp;
  const _Float16* Abase = xc + (size_t)bm * E_;
  const _Float16* Bbase = w + (size_t)bn * E_;
  f32x4 acc[4][4] = {};
  stageA256(Abase + 0, Asr, wid, lane);
  stageB128(Bbase + 0, Bsr, wid, lane);
  stageA256(Abase + 64, Asr + 256 * 64, wid, lane);
  stageB128(Bbase + 64, Bsr + 128 * 64, wid, lane);
  asm volatile("s_waitcnt vmcnt(6)" ::: "memory");
  __builtin_amdgcn_s_barrier();
  for (int t = 0; t < 16; ++t) {
    const int slot = t % 3;
    const _Float16* Ac = Asr + slot * (256 * 64);
    const _Float16* Bc = Bsr + slot * (128 * 64);
    half8v a[2][4], bfr[2][4];
#pragma unroll
    for (int kk = 0; kk < 2; ++kk) {
      const int so = ((kk * 4 + g) ^ sw) * 8;
#pragma unroll
      for (int i = 0; i < 4; ++i)
        a[kk][i] = *(const half8v*)&Ac[(wr * 64 + i * 16 + r16) * 64 + so];
#pragma unroll
      for (int j = 0; j < 4; ++j)
        bfr[kk][j] = *(const half8v*)&Bc[(wc * 64 + j * 16 + r16) * 64 + so];
    }
    if (t < 14) {
      const int s2 = (t + 2) % 3;
      stageA256(Abase + (size_t)(t + 2) * 64, Asr + s2 * (256 * 64), wid, lane);
      stageB128(Bbase + (size_t)(t + 2) * 64, Bsr + s2 * (128 * 64), wid, lane);
      asm volatile("s_waitcnt vmcnt(6)" ::: "memory");   // stage t+1 retired; t+2 in flight
    } else if (t == 14) {
      asm volatile("s_waitcnt vmcnt(0)" ::: "memory");   // final tile (15) landed
    }
    __builtin_amdgcn_s_setprio(1);
#pragma unroll
    for (int kk = 0; kk < 2; ++kk)
#pragma unroll
      for (int i = 0; i < 4; ++i)
#pragma unroll
        for (int j = 0; j < 4; ++j)
          acc[i][j] = MFMA16(a[kk][i], bfr[kk][j], acc[i][j]);
    __builtin_amdgcn_s_setprio(0);
    __builtin_amdgcn_s_barrier();   // broadcasts vmcnt guarantee; guards ring-slot reuse
  }
#pragma unroll
  for (int i = 0; i < 4; ++i) {
#pragma unroll
    for (int j = 0; j < 4; ++j) {
      const int gn = bn + wc * 64 + j * 16 + r16;
      const float bb2 = bias[gn];
      const int h = gn >> 6, d = gn & 63;
      const int gm0 = bm + wr * 64 + i * 16 + g * 4;
      const int b_ = gm0 >> 11, s0 = gm0 & (S_ - 1);
      const size_t bhbase = (size_t)(b_ * H_ + h) * S_ * D_;
      if (z == 2) {
        half4v v4;
#pragma unroll
        for (int ii = 0; ii < 4; ++ii) v4[ii] = (_Float16)(acc[i][j][ii] + bb2);
        *(half4v*)&Vc[bhbase + (size_t)(s0 >> 4) * (D_ * 16) + d * 16 + (s0 & 15)] = v4;
      } else if (z == 1) {
#pragma unroll
        for (int ii = 0; ii < 4; ++ii) {
          const int s = s0 + ii;
          Kc[bhbase + (size_t)(s >> 5) * 2048 + (d >> 4) * 512 + (s & 31) * 16 + (d & 15)] =
              (_Float16)(acc[i][j][ii] + bb2);
        }
      } else {
#pragma unroll
        for (int ii = 0; ii < 4; ++ii)
          Qc[bhbase + (size_t)(s0 + ii) * D_ + d] = (_Float16)((acc[i][j][ii] + bb2) * QSCALE);
      }
    }
  }
}

// ---------------- flash attention v15: k-split x4, tree merge, 64 q-rows/block ----------------
__global__ __launch_bounds__(512) void attn_kernel(
    const _Float16* __restrict__ Qc, const _Float16* __restrict__ Kc, const _Float16* __restrict__ Vc,
    const _Float16* __restrict__ maskc, const int* __restrict__ nkpa,
    _Float16* __restrict__ Oc) {
  __shared__ float mlds[2][2][64][36];
  _Float16* smask = (_Float16*)&mlds[0][0][0][0];
  const int tid = threadIdx.x, lane = tid & 63, wid = tid >> 6;
  const int c = lane & 31, hi = lane >> 5;
  const int qg = wid & 1, kh = wid >> 1;
  const int id = blockIdx.x;
  const int slot = id & 7, hbh = (id >> 3) & 7, t = id >> 6;
  const int hb = hbh * 8 + slot;
  const int b = hb >> 4, h = hb & 15;
  const int nkp = nkpa[b];
  if (t * 64 >= nkp) return;
  const size_t bh = (size_t)(b * H_ + h);
  const _Float16* Qb = Qc + bh * S_ * D_;
  const _Float16* Kb = Kc + bh * S_ * D_;
  const _Float16* Vb = Vc + bh * S_ * D_;

  *((half4v*)smask + tid) = *((const half4v*)(maskc + (size_t)b * S_) + tid);

  const int jq = t * 64 + qg * 32 + c;

  half8v qb[4];
#pragma unroll
  for (int kc = 0; kc < 4; ++kc)
    qb[kc] = *(const half8v*)&Qb[(size_t)jq * D_ + 16 * kc + 8 * hi];

  half8v bone = {};
  if (hi == 0) bone[0] = (_Float16)1.0f;
  const f32x16 fzero = {};

  f32x16 oacc[2] = {};
  float mrun = -1e30f, lrun = 0.f;
  const int laneoff = c * 16 + 8 * hi;
  const int nkq = nkp >> 2;
  const int kb0 = kh * nkq;

  __syncthreads();

  half8v kaf[4];
  {
    const _Float16* ktb = Kb + (size_t)(kb0 >> 5) * 2048 + laneoff;
#pragma unroll
    for (int kc = 0; kc < 4; ++kc) kaf[kc] = *(const half8v*)&ktb[kc * 512];
  }
  _Float16 mv = smask[kb0 + c];

  for (int kb = kb0; kb < kb0 + nkq; kb += 32) {
    half8v amask = {};
    if (hi == 0) amask[0] = mv;
    __builtin_amdgcn_s_setprio(1);
    f32x16 sc = MFMA32(amask, bone, fzero);
    sc = MFMA32(kaf[0], qb[0], sc);
    sc = MFMA32(kaf[1], qb[1], sc);
    sc = MFMA32(kaf[2], qb[2], sc);
    sc = MFMA32(kaf[3], qb[3], sc);
    __builtin_amdgcn_s_setprio(0);
    const int kbn = (kb + 32 < kb0 + nkq) ? kb + 32 : kb0;
    {
      const _Float16* ktb = Kb + (size_t)(kbn >> 5) * 2048 + laneoff;
#pragma unroll
      for (int kc = 0; kc < 4; ++kc) kaf[kc] = *(const half8v*)&ktb[kc * 512];
    }
    mv = smask[kbn + c];
    const _Float16* v_base = Vb + (size_t)(kb >> 4) * (D_ * 16) + laneoff;
    half8v va00 = *(const half8v*)&v_base[0];
    half8v va01 = *(const half8v*)&v_base[512];
    half8v va10 = *(const half8v*)&v_base[1024];
    half8v va11 = *(const half8v*)&v_base[1024 + 512];
    float t0 = fmaxf(sc[0], sc[4]), t1 = fmaxf(sc[1], sc[5]);
    float t2 = fmaxf(sc[2], sc[6]), t3 = fmaxf(sc[3], sc[7]);
    t0 = fmaxf(fmaxf(sc[8], sc[12]), t0);
    t1 = fmaxf(fmaxf(sc[9], sc[13]), t1);
    t2 = fmaxf(fmaxf(sc[10], sc[14]), t2);
    t3 = fmaxf(fmaxf(sc[11], sc[15]), t3);
    float pmax = fmaxf(fmaxf(t0, t1), fmaxf(t2, t3));
    pmax = fmaxf(pmax, partner32(pmax, hi));
    if (__any(pmax > mrun + 11.0f)) {
      float mnew = fmaxf(mrun, pmax);
      float corr = __builtin_amdgcn_exp2f(mrun - mnew);
      mrun = mnew;
      lrun *= corr;
#pragma unroll
      for (int dt = 0; dt < 2; ++dt)
#pragma unroll
        for (int r = 0; r < 16; ++r) oacc[dt][r] *= corr;
    }
    float ps0 = 0.f, ps1 = 0.f;
#pragma unroll
    for (int sl = 0; sl < 2; ++sl) {
      const int bs = 8 * sl;
      float p0 = __builtin_amdgcn_exp2f(sc[bs + 0] - mrun);
      float p1 = __builtin_amdgcn_exp2f(sc[bs + 1] - mrun);
      float p2 = __builtin_amdgcn_exp2f(sc[bs + 2] - mrun);
      float p3 = __builtin_amdgcn_exp2f(sc[bs + 3] - mrun);
      float p4 = __builtin_amdgcn_exp2f(sc[bs + 4] - mrun);
      float p5 = __builtin_amdgcn_exp2f(sc[bs + 5] - mrun);
      float p6 = __builtin_amdgcn_exp2f(sc[bs + 6] - mrun);
      float p7 = __builtin_amdgcn_exp2f(sc[bs + 7] - mrun);
      ps0 += (p0 + p1) + (p2 + p3);
      ps1 += (p4 + p5) + (p6 + p7);
      unsigned uA = cvt_pk_u32(p0, p1);
      unsigned uB = cvt_pk_u32(p2, p3);
      unsigned uC = cvt_pk_u32(p4, p5);
      unsigned uD = cvt_pk_u32(p6, p7);
      unsigned w0, w1, w2, w3;
      pl32_swap(uA, uC, w0, w2);
      pl32_swap(uB, uD, w1, w3);
      uint4v u4 = {w0, w1, w2, w3};
      half8v pb = __builtin_bit_cast(half8v, u4);
      __builtin_amdgcn_s_setprio(1);
      oacc[0] = MFMA32(sl ? va10 : va00, pb, oacc[0]);
      oacc[1] = MFMA32(sl ? va11 : va01, pb, oacc[1]);
      __builtin_amdgcn_s_setprio(0);
    }
    lrun += ps0 + ps1;
  }
  lrun += partner32(lrun, hi);
  __syncthreads();
  if (kh >= 2) {
    float* p = &mlds[qg][kh - 2][lane][0];
#pragma unroll
    for (int dt = 0; dt < 2; ++dt)
#pragma unroll
      for (int rr = 0; rr < 4; ++rr) {
        float4 v4 = make_float4(oacc[dt][4 * rr], oacc[dt][4 * rr + 1],
                                oacc[dt][4 * rr + 2], oacc[dt][4 * rr + 3]);
        *(float4*)&p[dt * 16 + rr * 4] = v4;
      }
    p[32] = mrun;
    p[33] = lrun;
  }
  __syncthreads();
  if (kh < 2) {
    const float* p = &mlds[qg][kh][lane][0];
    const float mB = p[32], lB = p[33];
    const float mS = fmaxf(mrun, mB);
    const float cA = __builtin_amdgcn_exp2f(mrun - mS);
    const float cB = __builtin_amdgcn_exp2f(mB - mS);
#pragma unroll
    for (int dt = 0; dt < 2; ++dt)
#pragma unroll
      for (int rr = 0; rr < 4; ++rr) {
        float4 vB = *(const float4*)&p[dt * 16 + rr * 4];
        oacc[dt][4 * rr + 0] = oacc[dt][4 * rr + 0] * cA + vB.x * cB;
        oacc[dt][4 * rr + 1] = oacc[dt][4 * rr + 1] * cA + vB.y * cB;
        oacc[dt][4 * rr + 2] = oacc[dt][4 * rr + 2] * cA + vB.z * cB;
        oacc[dt][4 * rr + 3] = oacc[dt][4 * rr + 3] * cA + vB.w * cB;
      }
    lrun = lrun * cA + lB * cB;
    mrun = mS;
  }
  __syncthreads();
  if (kh == 1) {
    float* p = &mlds[qg][0][lane][0];
#pragma unroll
    for (int dt = 0; dt < 2; ++dt)
#pragma unroll
      for (int rr = 0; rr < 4; ++rr) {
        float4 v4 = make_float4(oacc[dt][4 * rr], oacc[dt][4 * rr + 1],
                                oacc[dt][4 * rr + 2], oacc[dt][4 * rr + 3]);
        *(float4*)&p[dt * 16 + rr * 4] = v4;
      }
    p[32] = mrun;
    p[33] = lrun;
  }
  __syncthreads();
  if (kh == 0) {
    const float* p = &mlds[qg][0][lane][0];
    const float mB = p[32], lB = p[33];
    const float mS = fmaxf(mrun, mB);
    const float cA = __builtin_amdgcn_exp2f(mrun - mS);
    const float cB = __builtin_amdgcn_exp2f(mB - mS);
    const float inv = 1.0f / (lrun * cA + lB * cB);
    const float fA = cA * inv, fB = cB * inv;
    _Float16* orow = Oc + ((size_t)(b * S_ + jq)) * E_ + h * D_;
#pragma unroll
    for (int dt = 0; dt < 2; ++dt)
#pragma unroll
      for (int rr = 0; rr < 4; ++rr) {
        float4 vB = *(const float4*)&p[dt * 16 + rr * 4];
        half4v o4;
        o4[0] = (_Float16)(oacc[dt][4 * rr + 0] * fA + vB.x * fB);
        o4[1] = (_Float16)(oacc[dt][4 * rr + 1] * fA + vB.y * fB);
        o4[2] = (_Float16)(oacc[dt][4 * rr + 2] * fA + vB.z * fB);
        o4[3] = (_Float16)(oacc[dt][4 * rr + 3] * fA + vB.w * fB);
        *(half4v*)&orow[32 * dt + 8 * rr + 4 * hi] = o4;
      }
  }
}

// ---------------- output projection: 64x128, BK=64 swizzled, dbuf, row scatter ----------------
__global__ __launch_bounds__(256) void oproj_gemm(
    const _Float16* __restrict__ Oc, const _Float16* __restrict__ wo, const float* __restrict__ bo,
    const int* __restrict__ ks, const int* __restrict__ nkpa, float* __restrict__ out) {
  const int id = blockIdx.x;
  const int jt = id / 32;
  const int rem = id % 32;
  const int bb = rem / 8, by = rem % 8;
  if (jt * 64 >= nkpa[bb]) return;
  __shared__ _Float16 As[2][64 * 64];
  __shared__ _Float16 Bs[2][128 * 64];
  const int tid = threadIdx.x, lane = tid & 63, wid = tid >> 6;
  const int g = lane >> 4, r16 = lane & 15;
  const int bm = bb * 2048 + jt * 64, bn = by * 128;
  const int wr = wid >> 1, wc = wid & 1;
  const int sw = r16 & 7;
  f32x4 acc[2][4] = {};
  stageX64s<64>(Oc + (size_t)bm * E_, E_, As[0], wid, lane);
  stageX64s<128>(wo + (size_t)bn * E_, E_, Bs[0], wid, lane);
  __syncthreads();
  int cur = 0;
  for (int k0 = 0; k0 < E_; k0 += 64) {
    const int kn = k0 + 64;
    if (kn < E_) {
      stageX64s<64>(Oc + (size_t)bm * E_ + kn, E_, As[cur ^ 1], wid, lane);
      stageX64s<128>(wo + (size_t)bn * E_ + kn, E_, Bs[cur ^ 1], wid, lane);
    }
    const _Float16* Ac = As[cur];
    const _Float16* Bc = Bs[cur];
#pragma unroll
    for (int kk = 0; kk < 2; ++kk) {
      const int so = ((kk * 4 + g) ^ sw) * 8;
      half8v a[2], bf[4];
#pragma unroll
      for (int i = 0; i < 2; ++i) a[i] = *(const half8v*)&Ac[(wr * 32 + i * 16 + r16) * 64 + so];
#pragma unroll
      for (int j = 0; j < 4; ++j) bf[j] = *(const half8v*)&Bc[(wc * 64 + j * 16 + r16) * 64 + so];
#pragma unroll
      for (int i = 0; i < 2; ++i)
#pragma unroll
        for (int j = 0; j < 4; ++j) acc[i][j] = MFMA16(a[i], bf[j], acc[i][j]);
    }
    __syncthreads();
    cur ^= 1;
  }
#pragma unroll
  for (int i = 0; i < 2; ++i) {
#pragma unroll
    for (int j = 0; j < 4; ++j) {
      const int gn = bn + wc * 64 + j * 16 + r16;
      const float bb2 = bo[gn];
      const int gm0 = bm + wr * 32 + i * 16 + g * 4;
#pragma unroll
      for (int ii = 0; ii < 4; ++ii) {
        const int gm = gm0 + ii;
        const int b_ = gm >> 11, j_ = gm & (S_ - 1);
        const int sorig = ks[b_ * 2048 + j_];
        const float y = acc[i][j][ii] + bb2;
        out[((size_t)(b_ * S_ + sorig)) * E_ + gn] = fabsf(y);
      }
    }
  }
}

extern "C" void kernel_launch(void* const* d_in, const int* in_sizes, int n_in,
                              void* d_out, int out_size, void* d_ws, size_t ws_size,
                              hipStream_t stream) {
  const float* x = (const float*)d_in[0];
  const unsigned char* mask = (const unsigned char*)d_in[1];
  const float* WQ_w = (const float*)d_in[2];
  const float* WQ_b = (const float*)d_in[3];
  const float* WK_w = (const float*)d_in[4];
  const float* WK_b = (const float*)d_in[5];
  const float* WV_w = (const float*)d_in[6];
  const float* WV_b = (const float*)d_in[7];
  const float* WO_w = (const float*)d_in[8];
  const float* WO_b = (const float*)d_in[9];

  char* ws = (char*)d_ws;
  size_t off = 0;
  _Float16* xc  = (_Float16*)(ws + off); off += (size_t)MTOT * E_ * 2;
  _Float16* wqh = (_Float16*)(ws + off); off += (size_t)E_ * E_ * 2;
  _Float16* wkh = (_Float16*)(ws + off); off += (size_t)E_ * E_ * 2;
  _Float16* wvh = (_Float16*)(ws + off); off += (size_t)E_ * E_ * 2;
  _Float16* woh = (_Float16*)(ws + off); off += (size_t)E_ * E_ * 2;
  _Float16* Qc  = (_Float16*)(ws + off); off += (size_t)MTOT * E_ * 2;
  _Float16* Kc  = (_Float16*)(ws + off); off += (size_t)MTOT * E_ * 2;
  _Float16* Vc  = (_Float16*)(ws + off); off += (size_t)MTOT * E_ * 2;
  _Float16* Oc  = (_Float16*)(ws + off); off += (size_t)MTOT * E_ * 2;
  _Float16* maskcf = (_Float16*)(ws + off); off += (size_t)B_ * S_ * 2;
  float* qmaskf = (float*)(ws + off); off += (size_t)B_ * S_ * 4;
  int* ksl      = (int*)(ws + off); off += (size_t)B_ * S_ * 4;
  int* nkpa     = (int*)(ws + off); off += 64;
  if (ws_size < off) return;

  mask_prep_w<<<dim3(4100), dim3(256), 0, stream>>>(
      mask, maskcf, qmaskf, ksl, nkpa,
      WQ_w, WK_w, WV_w, WO_w, wqh, wkh, wvh, woh);
  prep_fused<<<dim3(16384), dim3(256), 0, stream>>>(
      x, ksl, nkpa, xc, qmaskf, (float*)d_out);
  qkv_gemm<<<dim3(768), dim3(512), 0, stream>>>(
      xc, nkpa, wqh, wkh, wvh, WQ_b, WK_b, WV_b, Qc, Kc, Vc);
  attn_kernel<<<dim3((S_ / 64) * H_ * B_), dim3(512), 0, stream>>>(
      Qc, Kc, Vc, maskcf, nkpa, Oc);
  oproj_gemm<<<dim3(32 * 32), dim3(256), 0, stream>>>(Oc, woh, WO_b, ksl, nkpa, (float*)d_out);
}